// Round 1
// baseline (227.213 us; speedup 1.0000x reference)
//
#include <hip/hip_runtime.h>
#include <cstdint>
#include <cstddef>

// Problem constants (fixed shapes for this problem; host derives & trusts)
constexpr int O_C = 16;      // objects per image
constexpr int P_MAX = 8732;  // priors (LDS arrays sized for this)

__device__ __forceinline__ float waveMaxF(float v) {
    #pragma unroll
    for (int off = 32; off; off >>= 1) v = fmaxf(v, __shfl_xor(v, off));
    return v;
}
__device__ __forceinline__ float waveSumF(float v) {
    #pragma unroll
    for (int off = 32; off; off >>= 1) v += __shfl_xor(v, off);
    return v;
}
__device__ __forceinline__ int waveSumI(int v) {
    #pragma unroll
    for (int off = 32; off; off >>= 1) v += __shfl_xor(v, off);
    return v;
}

// ---------------------------------------------------------------------------
// Kernel A: per-batch matching. One block (256 thr) per batch image.
// Produces lab[B,P], n_pos[B], loc_abs[B] (sum |pred - gcxgcy| over pos).
// ---------------------------------------------------------------------------
__global__ __launch_bounds__(256) void match_kernel(
    const float* __restrict__ predict_locs,   // [B,P,4]
    const float* __restrict__ target_boxes,   // [B,O,4] xyxy
    const int*   __restrict__ target_labels,  // [B,O]
    const float* __restrict__ priors,         // [P,4] cxcywh
    int*   __restrict__ lab_out,              // [B,P]
    int*   __restrict__ n_pos,                // [B]
    float* __restrict__ loc_abs,              // [B]
    int P)
{
    const int b    = blockIdx.x;
    const int tid  = threadIdx.x;
    const int lane = tid & 63;
    const int wid  = tid >> 6;

    __shared__ float bx0[O_C], by0[O_C], bx1[O_C], by1[O_C], barea[O_C];
    __shared__ int   blab[O_C];
    __shared__ float s_ov[P_MAX];
    __shared__ unsigned char s_obj[P_MAX];
    __shared__ unsigned long long s_wb[O_C * 4];
    __shared__ int   s_oprior[O_C];
    __shared__ float s_facc[4];
    __shared__ int   s_iacc[4];

    if (tid < O_C) {
        const float* tb = target_boxes + ((size_t)b * O_C + tid) * 4;
        float x0 = tb[0], y0 = tb[1], x1 = tb[2], y1 = tb[3];
        bx0[tid] = x0; by0[tid] = y0; bx1[tid] = x1; by1[tid] = y1;
        barea[tid] = (x1 - x0) * (y1 - y0);
        blab[tid]  = target_labels[(size_t)b * O_C + tid];
    }
    __syncthreads();

    // per-thread best prior per object: key = (iou_bits << 32) | (~p)
    unsigned long long bestkey[O_C];
    #pragma unroll
    for (int o = 0; o < O_C; ++o) bestkey[o] = 0ull;

    for (int p = tid; p < P; p += 256) {
        float4 pr = reinterpret_cast<const float4*>(priors)[p];
        // cxcywh -> xyxy exactly like reference (mul by 0.5 exact)
        float px0 = pr.x - pr.z * 0.5f, py0 = pr.y - pr.w * 0.5f;
        float px1 = pr.x + pr.z * 0.5f, py1 = pr.y + pr.w * 0.5f;
        float parea = (px1 - px0) * (py1 - py0);
        float bv = -1.0f; int bo = 0;
        #pragma unroll
        for (int o = 0; o < O_C; ++o) {
            float ix0 = fmaxf(px0, bx0[o]), iy0 = fmaxf(py0, by0[o]);
            float ix1 = fminf(px1, bx1[o]), iy1 = fminf(py1, by1[o]);
            float iw = fmaxf(ix1 - ix0, 0.0f), ih = fmaxf(iy1 - iy0, 0.0f);
            float inter = iw * ih;
            float iou = inter / (barea[o] + parea - inter);
            if (iou > bv) { bv = iou; bo = o; }   // first-max wins (jnp.argmax)
            unsigned long long key =
                ((unsigned long long)__float_as_uint(iou) << 32) |
                (unsigned long long)(0xFFFFFFFFu - (unsigned)p); // ties -> smaller p
            if (key > bestkey[o]) bestkey[o] = key;
        }
        s_ov[p]  = bv;
        s_obj[p] = (unsigned char)bo;
    }

    // reduce per-object best prior across the block
    #pragma unroll
    for (int o = 0; o < O_C; ++o) {
        unsigned long long k = bestkey[o];
        #pragma unroll
        for (int off = 32; off; off >>= 1) {
            unsigned long long k2 = __shfl_xor(k, off);
            if (k2 > k) k = k2;
        }
        if (lane == 0) s_wb[o * 4 + wid] = k;
    }
    __syncthreads();
    if (tid < O_C) {
        unsigned long long k = s_wb[tid * 4];
        #pragma unroll
        for (int w = 1; w < 4; ++w) if (s_wb[tid * 4 + w] > k) k = s_wb[tid * 4 + w];
        s_oprior[tid] = (int)(0xFFFFFFFFu - (unsigned)(k & 0xFFFFFFFFull));
    }
    __syncthreads();

    // phase 2: labels + loc loss contribution
    int   cnt = 0;
    float acc = 0.0f;
    for (int p = tid; p < P; p += 256) {
        float ov = s_ov[p];
        int   obj = s_obj[p];
        #pragma unroll
        for (int o = 0; o < O_C; ++o) {        // ascending -> last write wins (np)
            if (s_oprior[o] == p) { obj = o; ov = 1.0f; }
        }
        int l = (ov < 0.5f) ? 0 : blab[obj];
        lab_out[(size_t)b * P + p] = l;
        if (l != 0) {
            ++cnt;
            float4 pr = reinterpret_cast<const float4*>(priors)[p];
            float x0 = bx0[obj], y0 = by0[obj], x1 = bx1[obj], y1 = by1[obj];
            float cx = (x0 + x1) * 0.5f, cy = (y0 + y1) * 0.5f;
            float w  = x1 - x0,          h  = y1 - y0;
            float g0 = (cx - pr.x) / (pr.z * 0.1f);
            float g1 = (cy - pr.y) / (pr.w * 0.1f);
            float g2 = logf(w / pr.z) / 0.2f;
            float g3 = logf(h / pr.w) / 0.2f;
            float4 pl = reinterpret_cast<const float4*>(predict_locs)[(size_t)b * P + p];
            acc += fabsf(pl.x - g0) + fabsf(pl.y - g1) +
                   fabsf(pl.z - g2) + fabsf(pl.w - g3);
        }
    }
    acc = waveSumF(acc);
    cnt = waveSumI(cnt);
    if (lane == 0) { s_facc[wid] = acc; s_iacc[wid] = cnt; }
    __syncthreads();
    if (tid == 0) {
        n_pos[b]   = s_iacc[0] + s_iacc[1] + s_iacc[2] + s_iacc[3];
        loc_abs[b] = s_facc[0] + s_facc[1] + s_facc[2] + s_facc[3];
    }
}

// ---------------------------------------------------------------------------
// Kernel B: cross-entropy per (b,p). One wave per row (81 classes).
// ce = max + log(sum exp(x-max)) - x[label]
// ---------------------------------------------------------------------------
__global__ __launch_bounds__(256) void ce_kernel(
    const float* __restrict__ confs,  // [rows, C]
    const int*   __restrict__ lab,    // [rows]
    float* __restrict__ ce,           // [rows]
    int rows, int C)
{
    const int lane = threadIdx.x & 63;
    const int gw   = (blockIdx.x * blockDim.x + threadIdx.x) >> 6;
    const int nw   = (gridDim.x * blockDim.x) >> 6;
    for (int row = gw; row < rows; row += nw) {
        const float* x = confs + (size_t)row * C;
        float v0 = x[lane];                                  // lane < 64 < C
        bool  h1 = (lane + 64) < C;
        float v1 = h1 ? x[lane + 64] : -3.0e38f;
        float m = waveMaxF(fmaxf(v0, v1));
        float s = expf(v0 - m) + (h1 ? expf(v1 - m) : 0.0f);
        s = waveSumF(s);
        int l = lab[row];
        float xl = (l < 64) ? __shfl(v0, l) : __shfl(v1, l - 64);
        if (lane == 0) ce[row] = m + logf(s) - xl;
    }
}

// ---------------------------------------------------------------------------
// Kernel C: per-batch hard-negative mining. One block per batch.
// Exact top-K sum via MSB-first radix select on float bit patterns.
// Also produces ce_pos[b] deterministically.
// ---------------------------------------------------------------------------
__global__ __launch_bounds__(256) void hard_kernel(
    const float* __restrict__ ce,      // [B,P]
    const int*   __restrict__ lab,     // [B,P]
    const int*   __restrict__ n_pos_a, // [B]
    float* __restrict__ ce_pos,        // [B]
    float* __restrict__ ce_hard,       // [B]
    int P)
{
    const int b    = blockIdx.x;
    const int tid  = threadIdx.x;
    const int lane = tid & 63;
    const int wid  = tid >> 6;

    __shared__ float s_v[P_MAX];
    __shared__ unsigned int hist[256];
    __shared__ unsigned int s_sel;
    __shared__ int s_kr;
    __shared__ float s_f[4], s_f2[4];

    const size_t base = (size_t)b * P;
    float possum = 0.0f, negsum = 0.0f;
    for (int p = tid; p < P; p += 256) {
        float c = ce[base + p];
        int   l = lab[base + p];
        float v;
        if (l != 0) { possum += c; v = 0.0f; }
        else        { negsum += c; v = c; }
        s_v[p] = v;
    }
    possum = waveSumF(possum);
    negsum = waveSumF(negsum);
    if (lane == 0) { s_f[wid] = possum; s_f2[wid] = negsum; }
    __syncthreads();
    float negsum_t = s_f2[0] + s_f2[1] + s_f2[2] + s_f2[3];
    if (tid == 0) ce_pos[b] = s_f[0] + s_f[1] + s_f[2] + s_f[3];

    const int K = 3 * n_pos_a[b];
    if (K <= 0) { if (tid == 0) ce_hard[b] = 0.0f; return; }
    if (K >= P) { if (tid == 0) ce_hard[b] = negsum_t; return; }
    __syncthreads();

    // radix select: find bit pattern of the K-th largest value (nonneg floats)
    unsigned int prefix = 0; int kr = K;
    for (int shift = 24; shift >= 0; shift -= 8) {
        hist[tid] = 0;
        __syncthreads();
        unsigned int maskHi = (shift == 24) ? 0u : (0xFFFFFFFFu << (shift + 8));
        for (int p = tid; p < P; p += 256) {
            unsigned int u = __float_as_uint(s_v[p]);
            if ((u & maskHi) == prefix) atomicAdd(&hist[(u >> shift) & 255], 1u);
        }
        __syncthreads();
        if (tid == 0) {
            unsigned int cum = 0; int sel = 0;
            for (int byte = 255; byte >= 0; --byte) {
                unsigned int c = hist[byte];
                if (cum + c >= (unsigned)kr) { sel = byte; break; }
                cum += c;
            }
            s_sel = prefix | ((unsigned)sel << shift);
            s_kr  = kr - (int)cum;
        }
        __syncthreads();
        prefix = s_sel; kr = s_kr;
        __syncthreads();
    }

    // sum of values strictly greater than threshold + kr copies of threshold
    float sumgt = 0.0f;
    for (int p = tid; p < P; p += 256) {
        unsigned int u = __float_as_uint(s_v[p]);
        if (u > prefix) sumgt += s_v[p];
    }
    sumgt = waveSumF(sumgt);
    if (lane == 0) s_f[wid] = sumgt;
    __syncthreads();
    if (tid == 0) {
        float sg = s_f[0] + s_f[1] + s_f[2] + s_f[3];
        ce_hard[b] = sg + (float)kr * __uint_as_float(prefix);
    }
}

// ---------------------------------------------------------------------------
// Kernel D: finalize scalar loss.
// ---------------------------------------------------------------------------
__global__ void finalize_kernel(
    const int*   __restrict__ n_pos,
    const float* __restrict__ ce_pos,
    const float* __restrict__ ce_hard,
    const float* __restrict__ loc_abs,
    float* __restrict__ out, int B)
{
    const int lane = threadIdx.x; // 64 threads
    int np = 0; float cp = 0.0f, ch = 0.0f, la = 0.0f;
    for (int b = lane; b < B; b += 64) {
        np += n_pos[b]; cp += ce_pos[b]; ch += ce_hard[b]; la += loc_abs[b];
    }
    #pragma unroll
    for (int off = 32; off; off >>= 1) {
        np += __shfl_xor(np, off);
        cp += __shfl_xor(cp, off);
        ch += __shfl_xor(ch, off);
        la += __shfl_xor(la, off);
    }
    if (lane == 0) {
        float npt = (float)np;
        out[0] = (ch + cp) / npt + la / (npt * 4.0f);
    }
}

extern "C" void kernel_launch(void* const* d_in, const int* in_sizes, int n_in,
                              void* d_out, int out_size, void* d_ws, size_t ws_size,
                              hipStream_t stream) {
    const float* predict_locs  = (const float*)d_in[0];
    const float* predict_confs = (const float*)d_in[1];
    const float* target_boxes  = (const float*)d_in[2];
    const int*   target_labels = (const int*)d_in[3];
    const float* priors        = (const float*)d_in[4];

    const int P = in_sizes[4] / 4;             // 8732
    const int B = in_sizes[0] / (P * 4);       // 64
    const int C = in_sizes[1] / (B * P);       // 81

    char* ws = (char*)d_ws;
    int*   lab     = (int*)ws;   ws += (size_t)B * P * sizeof(int);
    float* ce      = (float*)ws; ws += (size_t)B * P * sizeof(float);
    int*   n_pos   = (int*)ws;   ws += (size_t)B * sizeof(int);
    float* ce_pos  = (float*)ws; ws += (size_t)B * sizeof(float);
    float* ce_hard = (float*)ws; ws += (size_t)B * sizeof(float);
    float* loc_abs = (float*)ws; ws += (size_t)B * sizeof(float);

    match_kernel<<<B, 256, 0, stream>>>(predict_locs, target_boxes, target_labels,
                                        priors, lab, n_pos, loc_abs, P);
    const int rows = B * P;
    ce_kernel<<<4096, 256, 0, stream>>>(predict_confs, lab, ce, rows, C);
    hard_kernel<<<B, 256, 0, stream>>>(ce, lab, n_pos, ce_pos, ce_hard, P);
    finalize_kernel<<<1, 64, 0, stream>>>(n_pos, ce_pos, ce_hard, loc_abs,
                                          (float*)d_out, B);
}

// Round 2
// 151.847 us; speedup vs baseline: 1.4963x; 1.4963x over previous
//
#include <hip/hip_runtime.h>
#include <cstdint>
#include <cstddef>

constexpr int O_C = 16;      // objects per image
constexpr int P_MAX = 8732;  // priors (LDS arrays sized for this)

__device__ __forceinline__ float waveSumF(float v) {
    #pragma unroll
    for (int off = 32; off; off >>= 1) v += __shfl_xor(v, off);
    return v;
}
__device__ __forceinline__ int waveSumI(int v) {
    #pragma unroll
    for (int off = 32; off; off >>= 1) v += __shfl_xor(v, off);
    return v;
}

// ---------------------------------------------------------------------------
// Kernel A: per-batch matching. One block (1024 thr) per batch image.
// Produces lab[B,P], n_pos[B], loc_abs[B] (sum |pred - gcxgcy| over pos).
// ---------------------------------------------------------------------------
__global__ __launch_bounds__(1024) void match_kernel(
    const float* __restrict__ predict_locs,   // [B,P,4]
    const float* __restrict__ target_boxes,   // [B,O,4] xyxy
    const int*   __restrict__ target_labels,  // [B,O]
    const float* __restrict__ priors,         // [P,4] cxcywh
    int*   __restrict__ lab_out,              // [B,P]
    int*   __restrict__ n_pos,                // [B]
    float* __restrict__ loc_abs,              // [B]
    int P)
{
    const int b    = blockIdx.x;
    const int tid  = threadIdx.x;
    const int lane = tid & 63;
    const int wid  = tid >> 6;    // 0..15

    __shared__ float bx0[O_C], by0[O_C], bx1[O_C], by1[O_C], barea[O_C];
    __shared__ int   blab[O_C];
    __shared__ float s_ov[P_MAX];
    __shared__ unsigned char s_obj[P_MAX];
    __shared__ unsigned long long s_wb[O_C * 16];
    __shared__ int   s_oprior[O_C];
    __shared__ float s_facc[16];
    __shared__ int   s_iacc[16];

    if (tid < O_C) {
        const float* tb = target_boxes + ((size_t)b * O_C + tid) * 4;
        float x0 = tb[0], y0 = tb[1], x1 = tb[2], y1 = tb[3];
        bx0[tid] = x0; by0[tid] = y0; bx1[tid] = x1; by1[tid] = y1;
        barea[tid] = (x1 - x0) * (y1 - y0);
        blab[tid]  = target_labels[(size_t)b * O_C + tid];
    }
    __syncthreads();

    // per-thread best prior per object: key = (iou_bits << 32) | (~p)
    unsigned long long bestkey[O_C];
    #pragma unroll
    for (int o = 0; o < O_C; ++o) bestkey[o] = 0ull;

    for (int p = tid; p < P; p += 1024) {
        float4 pr = reinterpret_cast<const float4*>(priors)[p];
        float px0 = pr.x - pr.z * 0.5f, py0 = pr.y - pr.w * 0.5f;
        float px1 = pr.x + pr.z * 0.5f, py1 = pr.y + pr.w * 0.5f;
        float parea = (px1 - px0) * (py1 - py0);
        float bv = -1.0f; int bo = 0;
        #pragma unroll
        for (int o = 0; o < O_C; ++o) {
            float ix0 = fmaxf(px0, bx0[o]), iy0 = fmaxf(py0, by0[o]);
            float ix1 = fminf(px1, bx1[o]), iy1 = fminf(py1, by1[o]);
            float iw = fmaxf(ix1 - ix0, 0.0f), ih = fmaxf(iy1 - iy0, 0.0f);
            float inter = iw * ih;
            float iou = inter / (barea[o] + parea - inter);
            if (iou > bv) { bv = iou; bo = o; }   // first-max wins (argmax)
            unsigned long long key =
                ((unsigned long long)__float_as_uint(iou) << 32) |
                (unsigned long long)(0xFFFFFFFFu - (unsigned)p); // ties -> smaller p
            if (key > bestkey[o]) bestkey[o] = key;
        }
        s_ov[p]  = bv;
        s_obj[p] = (unsigned char)bo;
    }

    #pragma unroll
    for (int o = 0; o < O_C; ++o) {
        unsigned long long k = bestkey[o];
        #pragma unroll
        for (int off = 32; off; off >>= 1) {
            unsigned long long k2 = __shfl_xor(k, off);
            if (k2 > k) k = k2;
        }
        if (lane == 0) s_wb[o * 16 + wid] = k;
    }
    __syncthreads();
    if (tid < O_C) {
        unsigned long long k = s_wb[tid * 16];
        #pragma unroll
        for (int w = 1; w < 16; ++w) if (s_wb[tid * 16 + w] > k) k = s_wb[tid * 16 + w];
        s_oprior[tid] = (int)(0xFFFFFFFFu - (unsigned)(k & 0xFFFFFFFFull));
    }
    __syncthreads();

    // phase 2: labels + loc loss contribution
    int   cnt = 0;
    float acc = 0.0f;
    for (int p = tid; p < P; p += 1024) {
        float ov = s_ov[p];
        int   obj = s_obj[p];
        #pragma unroll
        for (int o = 0; o < O_C; ++o) {        // ascending -> last write wins (np)
            if (s_oprior[o] == p) { obj = o; ov = 1.0f; }
        }
        int l = (ov < 0.5f) ? 0 : blab[obj];
        lab_out[(size_t)b * P + p] = l;
        if (l != 0) {
            ++cnt;
            float4 pr = reinterpret_cast<const float4*>(priors)[p];
            float x0 = bx0[obj], y0 = by0[obj], x1 = bx1[obj], y1 = by1[obj];
            float cx = (x0 + x1) * 0.5f, cy = (y0 + y1) * 0.5f;
            float w  = x1 - x0,          h  = y1 - y0;
            float g0 = (cx - pr.x) / (pr.z * 0.1f);
            float g1 = (cy - pr.y) / (pr.w * 0.1f);
            float g2 = logf(w / pr.z) / 0.2f;
            float g3 = logf(h / pr.w) / 0.2f;
            float4 pl = reinterpret_cast<const float4*>(predict_locs)[(size_t)b * P + p];
            acc += fabsf(pl.x - g0) + fabsf(pl.y - g1) +
                   fabsf(pl.z - g2) + fabsf(pl.w - g3);
        }
    }
    acc = waveSumF(acc);
    cnt = waveSumI(cnt);
    if (lane == 0) { s_facc[wid] = acc; s_iacc[wid] = cnt; }
    __syncthreads();
    if (tid == 0) {
        int   c = 0; float a = 0.0f;
        #pragma unroll
        for (int w = 0; w < 16; ++w) { c += s_iacc[w]; a += s_facc[w]; }
        n_pos[b]   = c;
        loc_abs[b] = a;
    }
}

// ---------------------------------------------------------------------------
// Kernel B: cross-entropy, tile-staged. One block = 64 contiguous rows.
// Stage [64 x 81] floats in LDS (coalesced float4), 4 lanes per row reduce.
// Row stride 81 floats => 17 mod 32 banks, gcd(17,32)=1 -> conflict-free.
// ---------------------------------------------------------------------------
__global__ __launch_bounds__(256) void ce_kernel(
    const float* __restrict__ confs,  // [rows, C=81]
    const int*   __restrict__ lab,    // [rows]
    float* __restrict__ ce,           // [rows]
    int rows)
{
    constexpr int C = 81;
    constexpr int R = 64;                 // rows per block
    __shared__ float s_x[R * C];          // 20736 B

    const int tid   = threadIdx.x;
    const int block = blockIdx.x;
    const int row0  = block * R;

    // stage: 64*81 = 5184 floats = 1296 float4, contiguous & 16B-aligned
    {
        const float4* src = reinterpret_cast<const float4*>(confs + (size_t)row0 * C);
        float4* dst = reinterpret_cast<float4*>(s_x);
        const int nv = (R * C) / 4;       // 1296
        for (int i = tid; i < nv; i += 256) dst[i] = src[i];
    }
    __syncthreads();

    const int rl = tid >> 2;              // local row 0..63
    const int q  = tid & 3;               // quarter 0..3
    const int s  = q * 20 + (q > 0 ? 1 : 0);   // 0,21,41,61
    const int n  = q ? 20 : 21;
    const float* xr = s_x + rl * C;

    float v[21];
    #pragma unroll
    for (int i = 0; i < 21; ++i)
        v[i] = (i < n) ? xr[s + i] : -3.0e38f;

    float m = v[0];
    #pragma unroll
    for (int i = 1; i < 21; ++i) m = fmaxf(m, v[i]);
    m = fmaxf(m, __shfl_xor(m, 1));
    m = fmaxf(m, __shfl_xor(m, 2));

    float sum = 0.0f;
    #pragma unroll
    for (int i = 0; i < 21; ++i)
        if (i < n) sum += expf(v[i] - m);
    sum += __shfl_xor(sum, 1);
    sum += __shfl_xor(sum, 2);

    const int row = row0 + rl;
    if (q == 0 && row < rows) {
        int l = lab[row];
        ce[row] = m + logf(sum) - xr[l];
    }
}

// ---------------------------------------------------------------------------
// Kernel C: per-batch hard-negative mining (1024 thr). Exact top-K sum via
// MSB-first radix select on float bit patterns. Also ce_pos[b].
// ---------------------------------------------------------------------------
__global__ __launch_bounds__(1024) void hard_kernel(
    const float* __restrict__ ce,      // [B,P]
    const int*   __restrict__ lab,     // [B,P]
    const int*   __restrict__ n_pos_a, // [B]
    float* __restrict__ ce_pos,        // [B]
    float* __restrict__ ce_hard,       // [B]
    int P)
{
    const int b    = blockIdx.x;
    const int tid  = threadIdx.x;
    const int lane = tid & 63;
    const int wid  = tid >> 6;

    __shared__ float s_v[P_MAX];
    __shared__ unsigned int hist[256];
    __shared__ unsigned int s_sel;
    __shared__ int s_kr;
    __shared__ float s_f[16], s_f2[16];

    const size_t base = (size_t)b * P;
    float possum = 0.0f, negsum = 0.0f;
    for (int p = tid; p < P; p += 1024) {
        float c = ce[base + p];
        int   l = lab[base + p];
        float v;
        if (l != 0) { possum += c; v = 0.0f; }
        else        { negsum += c; v = c; }
        s_v[p] = v;
    }
    possum = waveSumF(possum);
    negsum = waveSumF(negsum);
    if (lane == 0) { s_f[wid] = possum; s_f2[wid] = negsum; }
    __syncthreads();
    float negsum_t = 0.0f, possum_t = 0.0f;
    #pragma unroll
    for (int w = 0; w < 16; ++w) { negsum_t += s_f2[w]; possum_t += s_f[w]; }
    if (tid == 0) ce_pos[b] = possum_t;

    const int K = 3 * n_pos_a[b];
    if (K <= 0) { if (tid == 0) ce_hard[b] = 0.0f; return; }
    if (K >= P) { if (tid == 0) ce_hard[b] = negsum_t; return; }
    __syncthreads();

    unsigned int prefix = 0; int kr = K;
    for (int shift = 24; shift >= 0; shift -= 8) {
        if (tid < 256) hist[tid] = 0;
        __syncthreads();
        unsigned int maskHi = (shift == 24) ? 0u : (0xFFFFFFFFu << (shift + 8));
        for (int p = tid; p < P; p += 1024) {
            unsigned int u = __float_as_uint(s_v[p]);
            if ((u & maskHi) == prefix) atomicAdd(&hist[(u >> shift) & 255], 1u);
        }
        __syncthreads();
        if (tid == 0) {
            unsigned int cum = 0; int sel = 0;
            for (int byte = 255; byte >= 0; --byte) {
                unsigned int c = hist[byte];
                if (cum + c >= (unsigned)kr) { sel = byte; break; }
                cum += c;
            }
            s_sel = prefix | ((unsigned)sel << shift);
            s_kr  = kr - (int)cum;
        }
        __syncthreads();
        prefix = s_sel; kr = s_kr;
        __syncthreads();
    }

    float sumgt = 0.0f;
    for (int p = tid; p < P; p += 1024) {
        unsigned int u = __float_as_uint(s_v[p]);
        if (u > prefix) sumgt += s_v[p];
    }
    sumgt = waveSumF(sumgt);
    if (lane == 0) s_f[wid] = sumgt;
    __syncthreads();
    if (tid == 0) {
        float sg = 0.0f;
        #pragma unroll
        for (int w = 0; w < 16; ++w) sg += s_f[w];
        ce_hard[b] = sg + (float)kr * __uint_as_float(prefix);
    }
}

// ---------------------------------------------------------------------------
// Kernel D: finalize scalar loss.
// ---------------------------------------------------------------------------
__global__ void finalize_kernel(
    const int*   __restrict__ n_pos,
    const float* __restrict__ ce_pos,
    const float* __restrict__ ce_hard,
    const float* __restrict__ loc_abs,
    float* __restrict__ out, int B)
{
    const int lane = threadIdx.x; // 64 threads
    int np = 0; float cp = 0.0f, ch = 0.0f, la = 0.0f;
    for (int b = lane; b < B; b += 64) {
        np += n_pos[b]; cp += ce_pos[b]; ch += ce_hard[b]; la += loc_abs[b];
    }
    #pragma unroll
    for (int off = 32; off; off >>= 1) {
        np += __shfl_xor(np, off);
        cp += __shfl_xor(cp, off);
        ch += __shfl_xor(ch, off);
        la += __shfl_xor(la, off);
    }
    if (lane == 0) {
        float npt = (float)np;
        out[0] = (ch + cp) / npt + la / (npt * 4.0f);
    }
}

extern "C" void kernel_launch(void* const* d_in, const int* in_sizes, int n_in,
                              void* d_out, int out_size, void* d_ws, size_t ws_size,
                              hipStream_t stream) {
    const float* predict_locs  = (const float*)d_in[0];
    const float* predict_confs = (const float*)d_in[1];
    const float* target_boxes  = (const float*)d_in[2];
    const int*   target_labels = (const int*)d_in[3];
    const float* priors        = (const float*)d_in[4];

    const int P = in_sizes[4] / 4;             // 8732
    const int B = in_sizes[0] / (P * 4);       // 64

    char* ws = (char*)d_ws;
    int*   lab     = (int*)ws;   ws += (size_t)B * P * sizeof(int);
    float* ce      = (float*)ws; ws += (size_t)B * P * sizeof(float);
    int*   n_pos   = (int*)ws;   ws += (size_t)B * sizeof(int);
    float* ce_pos  = (float*)ws; ws += (size_t)B * sizeof(float);
    float* ce_hard = (float*)ws; ws += (size_t)B * sizeof(float);
    float* loc_abs = (float*)ws; ws += (size_t)B * sizeof(float);

    match_kernel<<<B, 1024, 0, stream>>>(predict_locs, target_boxes, target_labels,
                                         priors, lab, n_pos, loc_abs, P);
    const int rows = B * P;                    // 558848, divisible by 64
    const int nblocks = (rows + 63) / 64;      // 8732
    ce_kernel<<<nblocks, 256, 0, stream>>>(predict_confs, lab, ce, rows);
    hard_kernel<<<B, 1024, 0, stream>>>(ce, lab, n_pos, ce_pos, ce_hard, P);
    finalize_kernel<<<1, 64, 0, stream>>>(n_pos, ce_pos, ce_hard, loc_abs,
                                          (float*)d_out, B);
}

// Round 3
// 86.799 us; speedup vs baseline: 2.6177x; 1.7494x over previous
//
#include <hip/hip_runtime.h>
#include <cstdint>
#include <cstddef>

constexpr int O_C = 16;      // objects per image
constexpr int P_MAX = 8732;  // priors
constexpr int CH   = 4;      // match chunks per batch
constexpr int CHP  = 2183;   // priors per chunk (4*2183 = 8732)

__device__ __forceinline__ float waveSumF(float v) {
    #pragma unroll
    for (int off = 32; off; off >>= 1) v += __shfl_xor(v, off);
    return v;
}
__device__ __forceinline__ int waveSumI(int v) {
    #pragma unroll
    for (int off = 32; off; off >>= 1) v += __shfl_xor(v, off);
    return v;
}

// ---------------------------------------------------------------------------
// init: zero the per-(b,o) argmax keys (atomicMax targets)
// ---------------------------------------------------------------------------
__global__ void init_okey(unsigned long long* __restrict__ okey, int n) {
    int i = threadIdx.x;
    for (; i < n; i += 256) okey[i] = 0ull;
}

// ---------------------------------------------------------------------------
// A1: per-prior IoU argmax over objects + per-object best-prior candidates.
// grid = B*CH blocks, 256 thr. Deterministic via commutative u64 atomicMax.
// ---------------------------------------------------------------------------
__global__ __launch_bounds__(256) void matchA1(
    const float* __restrict__ target_boxes,   // [B,O,4] xyxy
    const float* __restrict__ priors,         // [P,4] cxcywh
    float* __restrict__ ov_out,               // [B,P]
    unsigned char* __restrict__ obj_out,      // [B,P]
    unsigned long long* __restrict__ okey,    // [B,O]
    int P)
{
    const int b    = blockIdx.x / CH;
    const int c    = blockIdx.x % CH;
    const int tid  = threadIdx.x;
    const int lane = tid & 63;
    const int wid  = tid >> 6;

    __shared__ float bx0[O_C], by0[O_C], bx1[O_C], by1[O_C], barea[O_C];
    __shared__ unsigned long long s_wb[O_C * 4];

    if (tid < O_C) {
        const float* tb = target_boxes + ((size_t)b * O_C + tid) * 4;
        float x0 = tb[0], y0 = tb[1], x1 = tb[2], y1 = tb[3];
        bx0[tid] = x0; by0[tid] = y0; bx1[tid] = x1; by1[tid] = y1;
        barea[tid] = (x1 - x0) * (y1 - y0);
    }
    __syncthreads();

    float bi[O_C]; int bp[O_C];
    #pragma unroll
    for (int o = 0; o < O_C; ++o) { bi[o] = -1.0f; bp[o] = 0; }

    const int p0 = c * CHP, p1 = p0 + CHP;
    for (int p = p0 + tid; p < p1; p += 256) {
        float4 pr = reinterpret_cast<const float4*>(priors)[p];
        float px0 = pr.x - pr.z * 0.5f, py0 = pr.y - pr.w * 0.5f;
        float px1 = pr.x + pr.z * 0.5f, py1 = pr.y + pr.w * 0.5f;
        float parea = (px1 - px0) * (py1 - py0);
        float bv = -1.0f; int bo = 0;
        #pragma unroll
        for (int o = 0; o < O_C; ++o) {
            float ix0 = fmaxf(px0, bx0[o]), iy0 = fmaxf(py0, by0[o]);
            float ix1 = fminf(px1, bx1[o]), iy1 = fminf(py1, by1[o]);
            float iw = fmaxf(ix1 - ix0, 0.0f), ih = fmaxf(iy1 - iy0, 0.0f);
            float inter = iw * ih;
            float iou = inter / (barea[o] + parea - inter);
            if (iou > bv) { bv = iou; bo = o; }       // first-max (argmax over o)
            if (iou > bi[o]) { bi[o] = iou; bp[o] = p; } // strict > keeps smallest p
        }
        ov_out[(size_t)b * P + p]  = bv;
        obj_out[(size_t)b * P + p] = (unsigned char)bo;
    }

    // reduce per-object candidates: key = iou_bits<<32 | ~p  (ties -> smaller p)
    #pragma unroll
    for (int o = 0; o < O_C; ++o) {
        unsigned long long k = (bi[o] >= 0.0f)
            ? (((unsigned long long)__float_as_uint(bi[o]) << 32) |
               (unsigned long long)(0xFFFFFFFFu - (unsigned)bp[o]))
            : 0ull;
        #pragma unroll
        for (int off = 32; off; off >>= 1) {
            unsigned long long k2 = __shfl_xor(k, off);
            if (k2 > k) k = k2;
        }
        if (lane == 0) s_wb[o * 4 + wid] = k;
    }
    __syncthreads();
    if (tid < O_C) {
        unsigned long long k = s_wb[tid * 4];
        #pragma unroll
        for (int w = 1; w < 4; ++w) if (s_wb[tid * 4 + w] > k) k = s_wb[tid * 4 + w];
        if (k) atomicMax(&okey[(size_t)b * O_C + tid], k);
    }
}

// ---------------------------------------------------------------------------
// A2: forced matches + labels + loc-loss partials. grid = B*CH, 256 thr.
// ---------------------------------------------------------------------------
__global__ __launch_bounds__(256) void matchA2(
    const float* __restrict__ predict_locs,   // [B,P,4]
    const float* __restrict__ target_boxes,   // [B,O,4]
    const int*   __restrict__ target_labels,  // [B,O]
    const float* __restrict__ priors,         // [P,4]
    const float* __restrict__ ov_in,          // [B,P]
    const unsigned char* __restrict__ obj_in, // [B,P]
    const unsigned long long* __restrict__ okey, // [B,O]
    int*   __restrict__ lab_out,              // [B,P]
    int*   __restrict__ npos_p,               // [B*CH]
    float* __restrict__ loc_p,                // [B*CH]
    int P)
{
    const int b    = blockIdx.x / CH;
    const int c    = blockIdx.x % CH;
    const int tid  = threadIdx.x;
    const int lane = tid & 63;
    const int wid  = tid >> 6;

    __shared__ float bx0[O_C], by0[O_C], bx1[O_C], by1[O_C];
    __shared__ int   blab[O_C], s_oprior[O_C];
    __shared__ float s_facc[4];
    __shared__ int   s_iacc[4];

    if (tid < O_C) {
        const float* tb = target_boxes + ((size_t)b * O_C + tid) * 4;
        bx0[tid] = tb[0]; by0[tid] = tb[1]; bx1[tid] = tb[2]; by1[tid] = tb[3];
        blab[tid] = target_labels[(size_t)b * O_C + tid];
        unsigned long long k = okey[(size_t)b * O_C + tid];
        s_oprior[tid] = (int)(0xFFFFFFFFu - (unsigned)(k & 0xFFFFFFFFull));
    }
    __syncthreads();

    int   cnt = 0;
    float acc = 0.0f;
    const int p0 = c * CHP, p1 = p0 + CHP;
    for (int p = p0 + tid; p < p1; p += 256) {
        float ov  = ov_in[(size_t)b * P + p];
        int   obj = obj_in[(size_t)b * P + p];
        #pragma unroll
        for (int o = 0; o < O_C; ++o) {        // ascending -> last write wins
            if (s_oprior[o] == p) { obj = o; ov = 1.0f; }
        }
        int l = (ov < 0.5f) ? 0 : blab[obj];
        lab_out[(size_t)b * P + p] = l;
        if (l != 0) {
            ++cnt;
            float4 pr = reinterpret_cast<const float4*>(priors)[p];
            float x0 = bx0[obj], y0 = by0[obj], x1 = bx1[obj], y1 = by1[obj];
            float cx = (x0 + x1) * 0.5f, cy = (y0 + y1) * 0.5f;
            float w  = x1 - x0,          h  = y1 - y0;
            float g0 = (cx - pr.x) / (pr.z * 0.1f);
            float g1 = (cy - pr.y) / (pr.w * 0.1f);
            float g2 = logf(w / pr.z) / 0.2f;
            float g3 = logf(h / pr.w) / 0.2f;
            float4 pl = reinterpret_cast<const float4*>(predict_locs)[(size_t)b * P + p];
            acc += fabsf(pl.x - g0) + fabsf(pl.y - g1) +
                   fabsf(pl.z - g2) + fabsf(pl.w - g3);
        }
    }
    acc = waveSumF(acc);
    cnt = waveSumI(cnt);
    if (lane == 0) { s_facc[wid] = acc; s_iacc[wid] = cnt; }
    __syncthreads();
    if (tid == 0) {
        npos_p[blockIdx.x] = s_iacc[0] + s_iacc[1] + s_iacc[2] + s_iacc[3];
        loc_p[blockIdx.x]  = s_facc[0] + s_facc[1] + s_facc[2] + s_facc[3];
    }
}

// ---------------------------------------------------------------------------
// B: cross-entropy, tile-staged, fast transcendentals.
// One block = 64 contiguous rows; 4 lanes per row from LDS.
// ---------------------------------------------------------------------------
__global__ __launch_bounds__(256) void ce_kernel(
    const float* __restrict__ confs,  // [rows, 81]
    const int*   __restrict__ lab,    // [rows]
    float* __restrict__ ce,           // [rows]
    int rows)
{
    constexpr int C = 81;
    constexpr int R = 64;
    __shared__ float s_x[R * C];

    const int tid  = threadIdx.x;
    const int row0 = blockIdx.x * R;

    {
        const float4* src = reinterpret_cast<const float4*>(confs + (size_t)row0 * C);
        float4* dst = reinterpret_cast<float4*>(s_x);
        const int nv = (R * C) / 4;       // 1296
        for (int i = tid; i < nv; i += 256) dst[i] = src[i];
    }
    __syncthreads();

    const int rl = tid >> 2;
    const int q  = tid & 3;
    const int s  = q * 20 + (q > 0 ? 1 : 0);   // 0,21,41,61
    const int n  = q ? 20 : 21;
    const float* xr = s_x + rl * C;

    float v[21];
    #pragma unroll
    for (int i = 0; i < 21; ++i)
        v[i] = (i < n) ? xr[s + i] : -3.0e38f;

    float m = v[0];
    #pragma unroll
    for (int i = 1; i < 21; ++i) m = fmaxf(m, v[i]);
    m = fmaxf(m, __shfl_xor(m, 1));
    m = fmaxf(m, __shfl_xor(m, 2));

    float sum = 0.0f;
    #pragma unroll
    for (int i = 0; i < 21; ++i)
        if (i < n) sum += __expf(v[i] - m);
    sum += __shfl_xor(sum, 1);
    sum += __shfl_xor(sum, 2);

    const int row = row0 + rl;
    if (q == 0 && row < rows) {
        int l = lab[row];
        ce[row] = m + __logf(sum) - xr[l];
    }
}

// ---------------------------------------------------------------------------
// C: per-batch hard-negative mining, 1024 thr. Privatized histograms +
// wave-parallel suffix-scan digit select. Exact top-K sum.
// ---------------------------------------------------------------------------
__global__ __launch_bounds__(1024) void hard_kernel(
    const float* __restrict__ ce,      // [B,P]
    const int*   __restrict__ lab,     // [B,P]
    const int*   __restrict__ npos_p,  // [B*CH]
    float* __restrict__ ce_pos,        // [B]
    float* __restrict__ ce_hard,       // [B]
    int P)
{
    const int b    = blockIdx.x;
    const int tid  = threadIdx.x;
    const int lane = tid & 63;
    const int wid  = tid >> 6;

    __shared__ float s_v[P_MAX];
    __shared__ unsigned int hist[16][256];
    __shared__ unsigned int s_sel;
    __shared__ int s_kr;
    __shared__ float s_f[16], s_f2[16];

    const size_t base = (size_t)b * P;
    float possum = 0.0f, negsum = 0.0f;
    for (int p = tid; p < P; p += 1024) {
        float c = ce[base + p];
        int   l = lab[base + p];
        float v;
        if (l != 0) { possum += c; v = 0.0f; }
        else        { negsum += c; v = c; }
        s_v[p] = v;
    }
    possum = waveSumF(possum);
    negsum = waveSumF(negsum);
    if (lane == 0) { s_f[wid] = possum; s_f2[wid] = negsum; }
    __syncthreads();
    float negsum_t = 0.0f, possum_t = 0.0f;
    #pragma unroll
    for (int w = 0; w < 16; ++w) { negsum_t += s_f2[w]; possum_t += s_f[w]; }
    if (tid == 0) ce_pos[b] = possum_t;

    const int K = 3 * (npos_p[b * CH] + npos_p[b * CH + 1] +
                       npos_p[b * CH + 2] + npos_p[b * CH + 3]);
    if (K <= 0) { if (tid == 0) ce_hard[b] = 0.0f; return; }
    if (K >= P) { if (tid == 0) ce_hard[b] = negsum_t; return; }

    unsigned int prefix = 0; int kr = K;
    for (int shift = 24; shift >= 0; shift -= 8) {
        for (int i = tid; i < 16 * 256; i += 1024) (&hist[0][0])[i] = 0;
        __syncthreads();
        unsigned int maskHi = (shift == 24) ? 0u : (0xFFFFFFFFu << (shift + 8));
        for (int p = tid; p < P; p += 1024) {
            unsigned int u = __float_as_uint(s_v[p]);
            if ((u & maskHi) == prefix) atomicAdd(&hist[wid][(u >> shift) & 255], 1u);
        }
        __syncthreads();
        if (wid == 0) {
            unsigned h0 = 0, h1 = 0, h2 = 0, h3 = 0;
            #pragma unroll 4
            for (int w = 0; w < 16; ++w) {
                h0 += hist[w][lane * 4 + 0];
                h1 += hist[w][lane * 4 + 1];
                h2 += hist[w][lane * 4 + 2];
                h3 += hist[w][lane * 4 + 3];
            }
            unsigned own = h0 + h1 + h2 + h3;
            unsigned t = own;                   // inclusive suffix over lanes
            #pragma unroll
            for (int off = 1; off < 64; off <<= 1) {
                unsigned u = __shfl_down(t, off);
                if (lane + off >= 64) u = 0;
                t += u;
            }
            unsigned Tnext = t - own;           // sum over lanes > this lane
            unsigned cum3 = Tnext;
            unsigned cum2 = cum3 + h3;
            unsigned cum1 = cum2 + h2;
            unsigned cum0 = cum1 + h1;
            unsigned kru = (unsigned)kr;
            int selj = -1; unsigned cg = 0, hs = 0;
            if      (cum3 < kru && kru <= cum3 + h3) { selj = 3; cg = cum3; }
            else if (cum2 < kru && kru <= cum2 + h2) { selj = 2; cg = cum2; }
            else if (cum1 < kru && kru <= cum1 + h1) { selj = 1; cg = cum1; }
            else if (cum0 < kru && kru <= cum0 + h0) { selj = 0; cg = cum0; }
            if (selj >= 0) {
                s_sel = prefix | ((unsigned)(lane * 4 + selj) << shift);
                s_kr  = kr - (int)cg;
            }
        }
        __syncthreads();
        prefix = s_sel; kr = s_kr;
        __syncthreads();
    }

    float sumgt = 0.0f;
    for (int p = tid; p < P; p += 1024) {
        unsigned int u = __float_as_uint(s_v[p]);
        if (u > prefix) sumgt += s_v[p];
    }
    sumgt = waveSumF(sumgt);
    if (lane == 0) s_f[wid] = sumgt;
    __syncthreads();
    if (tid == 0) {
        float sg = 0.0f;
        #pragma unroll
        for (int w = 0; w < 16; ++w) sg += s_f[w];
        ce_hard[b] = sg + (float)kr * __uint_as_float(prefix);
    }
}

// ---------------------------------------------------------------------------
// D: finalize scalar loss. Deterministic fixed-order sums.
// ---------------------------------------------------------------------------
__global__ void finalize_kernel(
    const int*   __restrict__ npos_p,   // [B*CH]
    const float* __restrict__ ce_pos,   // [B]
    const float* __restrict__ ce_hard,  // [B]
    const float* __restrict__ loc_p,    // [B*CH]
    float* __restrict__ out, int B)
{
    const int lane = threadIdx.x; // 64 threads
    int np = 0; float cp = 0.0f, ch = 0.0f, la = 0.0f;
    for (int b = lane; b < B; b += 64) {
        #pragma unroll
        for (int c = 0; c < CH; ++c) {
            np += npos_p[b * CH + c];
            la += loc_p[b * CH + c];
        }
        cp += ce_pos[b]; ch += ce_hard[b];
    }
    #pragma unroll
    for (int off = 32; off; off >>= 1) {
        np += __shfl_xor(np, off);
        cp += __shfl_xor(cp, off);
        ch += __shfl_xor(ch, off);
        la += __shfl_xor(la, off);
    }
    if (lane == 0) {
        float npt = (float)np;
        out[0] = (ch + cp) / npt + la / (npt * 4.0f);
    }
}

extern "C" void kernel_launch(void* const* d_in, const int* in_sizes, int n_in,
                              void* d_out, int out_size, void* d_ws, size_t ws_size,
                              hipStream_t stream) {
    const float* predict_locs  = (const float*)d_in[0];
    const float* predict_confs = (const float*)d_in[1];
    const float* target_boxes  = (const float*)d_in[2];
    const int*   target_labels = (const int*)d_in[3];
    const float* priors        = (const float*)d_in[4];

    const int P = in_sizes[4] / 4;             // 8732
    const int B = in_sizes[0] / (P * 4);       // 64

    char* ws = (char*)d_ws;
    unsigned long long* okey = (unsigned long long*)ws; ws += (size_t)B * O_C * sizeof(unsigned long long);
    int*   lab     = (int*)ws;   ws += (size_t)B * P * sizeof(int);
    float* ce      = (float*)ws; ws += (size_t)B * P * sizeof(float);
    float* ov      = (float*)ws; ws += (size_t)B * P * sizeof(float);
    int*   npos_p  = (int*)ws;   ws += (size_t)B * CH * sizeof(int);
    float* loc_p   = (float*)ws; ws += (size_t)B * CH * sizeof(float);
    float* ce_pos  = (float*)ws; ws += (size_t)B * sizeof(float);
    float* ce_hard = (float*)ws; ws += (size_t)B * sizeof(float);
    unsigned char* obj = (unsigned char*)ws; ws += (size_t)B * P;

    init_okey<<<1, 256, 0, stream>>>(okey, B * O_C);
    matchA1<<<B * CH, 256, 0, stream>>>(target_boxes, priors, ov, obj, okey, P);
    matchA2<<<B * CH, 256, 0, stream>>>(predict_locs, target_boxes, target_labels,
                                        priors, ov, obj, okey, lab, npos_p, loc_p, P);
    const int rows = B * P;                    // 558848, divisible by 64
    ce_kernel<<<rows / 64, 256, 0, stream>>>(predict_confs, lab, ce, rows);
    hard_kernel<<<B, 1024, 0, stream>>>(ce, lab, npos_p, ce_pos, ce_hard, P);
    finalize_kernel<<<1, 64, 0, stream>>>(npos_p, ce_pos, ce_hard, loc_p,
                                          (float*)d_out, B);
}